// Round 1
// 234.978 us; speedup vs baseline: 1.0255x; 1.0255x over previous
//
#include <hip/hip_runtime.h>

#define NT     111
#define LMAX   5
#define TAU    32
#define NBATCH 32
#define ROW    2304   // f32 elements per batch row of fs

struct Tup { int l, l1, l2, out_off, in1, in2; };
struct Meta { Tup t[NT]; int totch; };

constexpr int IN_OFF[LMAX + 1] = {0, 64, 256, 576, 1024, 1600};

constexpr Meta make_meta() {
  Meta m{};
  int n = 0, out = 0;
  for (int l = 0; l <= LMAX; ++l)
    for (int l1 = 0; l1 <= LMAX; ++l1)
      for (int l2 = 0; l2 <= LMAX; ++l2) {
        int df = l1 - l2; if (df < 0) df = -df;
        if (df <= l && l <= l1 + l2) {
          m.t[n].l = l; m.t[n].l1 = l1; m.t[n].l2 = l2;
          m.t[n].out_off = out;
          m.t[n].in1 = IN_OFF[l1]; m.t[n].in2 = IN_OFF[l2];
          out += TAU * TAU * (2 * l + 1);
          ++n;
        }
      }
  m.totch = out;
  return m;
}

constexpr Meta META  = make_meta();
constexpr int  TOTCH = META.totch;   // 789504 complex pairs per batch

// ---------- compile-time CG coefficients ----------
constexpr double cfact(int n) { double r = 1.0; for (int i = 2; i <= n; ++i) r *= i; return r; }

constexpr double csqrt(double x) {
  if (x <= 0.0) return 0.0;
  double g = x;
  for (int i = 0; i < 100; ++i) g = 0.5 * (g + x / g);  // Newton, converges to f64 ulp
  return g;
}

// Condon-Shortley CG coefficient <j1 m1 j2 m2 | j3 m3>, Racah formula, f64 exact factorials.
constexpr double cg_coef_ct(int j1, int m1, int j2, int m2, int j3, int m3) {
  if (m1 + m2 != m3) return 0.0;
  double pref = csqrt((2.0 * j3 + 1.0) * cfact(j3 + j1 - j2) * cfact(j3 - j1 + j2) *
                      cfact(j1 + j2 - j3) / cfact(j1 + j2 + j3 + 1));
  pref *= csqrt(cfact(j3 + m3) * cfact(j3 - m3) * cfact(j1 - m1) * cfact(j1 + m1) *
                cfact(j2 - m2) * cfact(j2 + m2));
  double s = 0.0;
  const int kmax = j1 + j2 - j3;
  for (int k = 0; k <= kmax; ++k) {
    const int a3 = j1 - m1 - k, a4 = j2 + m2 - k, a5 = j3 - j2 + m1 + k, a6 = j3 - j1 - m2 + k;
    if (a3 < 0 || a4 < 0 || a5 < 0 || a6 < 0) continue;
    const double den = cfact(k) * cfact(kmax - k) * cfact(a3) * cfact(a4) * cfact(a5) * cfact(a6);
    s += ((k & 1) ? -1.0 : 1.0) / den;
  }
  return pref * s;
}

// Per-tuple constexpr table (separate variable per tuple keeps each constexpr
// evaluation ~100k steps, under clang's per-initializer limit).
template<int L, int L1, int L2>
struct CGTab {
  struct T { float v[2 * L + 1][2 * L1 + 1][2 * L2 + 1]; };
  static constexpr T gen() {
    T t{};
    for (int m = 0; m < 2 * L + 1; ++m)
      for (int i1 = 0; i1 < 2 * L1 + 1; ++i1)
        for (int i2 = 0; i2 < 2 * L2 + 1; ++i2)
          t.v[m][i1][i2] = (float)cg_coef_ct(L1, i1 - L1, L2, i2 - L2, L, m - L);
    return t;
  }
  static constexpr T tab = gen();
};

// ---------- fully-unrolled per-tuple contraction ----------
// Thread t owns (t1,t2) pairs tp = t + 256*j, j=0..3; t2 = t&31 is j-invariant
// (b-fragment registers reused across all 4 j's). All compute loops unroll to
// straight-line FMAs with CG values as immediate constants.
//
// Store path: res[D] goes through split re/im LDS planes (lane stride D is odd
// -> <=2 lanes/bank on the writes, free per m136), then the block streams the
// contiguous 256*D*8B tile out as coalesced float4 (16 B/lane). This replaces
// the old per-thread float2 stores at 88B lane-stride (64 distinct lines per
// store instruction) which capped effective write BW at ~1.7 TB/s.
template<int L, int L1, int L2>
__device__ __forceinline__ void tuple_impl(const float* __restrict__ fa,
                                           const float* __restrict__ fb,
                                           float2* __restrict__ po,
                                           float* __restrict__ s_re,
                                           float* __restrict__ s_im) {
  constexpr int D = 2 * L + 1, D1 = 2 * L1 + 1, D2 = 2 * L2 + 1;
  const int tid = threadIdx.x;

  const int t2 = tid & 31;
  float br[D2], bi[D2];
  const float2* pb = (const float2*)fb + t2 * D2;
  #pragma unroll
  for (int i = 0; i < D2; ++i) { float2 v = pb[i]; br[i] = v.x; bi[i] = v.y; }

  #pragma unroll
  for (int j = 0; j < 4; ++j) {
    const int tp = tid + 256 * j;
    const int t1 = tp >> 5;

    float ar[D1], ai[D1];
    const float2* pa = (const float2*)fa + t1 * D1;
    #pragma unroll
    for (int i = 0; i < D1; ++i) { float2 v = pa[i]; ar[i] = v.x; ai[i] = v.y; }

    float2 res[D];
    #pragma unroll
    for (int m = 0; m < D; ++m) {
      float re = 0.f, im = 0.f;
      #pragma unroll
      for (int i1 = 0; i1 < D1; ++i1) {
        const int i2 = (m - L) - (i1 - L1) + L2;   // unroll-time constant
        if (i2 >= 0 && i2 < D2) {                   // folds after unrolling
          const float c = CGTab<L, L1, L2>::tab.v[m][i1][i2];  // immediate
          if (c != 0.f) {
            re += c * (ar[i1] * br[i2] - ai[i1] * bi[i2]);
            im += c * (ar[i1] * bi[i2] + ai[i1] * br[i2]);
          }
        }
      }
      res[m] = make_float2(re, im);
    }

    // ---- transpose through LDS, store coalesced ----
    __syncthreads();   // previous store-phase readers done before overwrite
    #pragma unroll
    for (int m = 0; m < D; ++m) {
      s_re[tid * D + m] = res[m].x;
      s_im[tid * D + m] = res[m].y;
    }
    __syncthreads();

    // contiguous tile for this j: 256*D float2 = 128*D float4, 16B-aligned
    float4* oj4 = (float4*)(po + (size_t)(256 * j) * D);
    constexpr int NV = 128 * D;                 // float4 count (D odd)
    #pragma unroll
    for (int k = 0; k < (NV + 255) / 256; ++k) {
      const int e = tid + 256 * k;
      if (e < NV) {
        oj4[e] = make_float4(s_re[2 * e], s_im[2 * e],
                             s_re[2 * e + 1], s_im[2 * e + 1]);
      }
    }
  }
}

// ---------- compile-time dispatch over the 111 tuples ----------
template<int I>
__device__ __forceinline__ void dispatch(int idx, int b,
                                         const float* __restrict__ fs,
                                         float2* __restrict__ out,
                                         float* __restrict__ s_re,
                                         float* __restrict__ s_im) {
  if constexpr (I < NT) {
    if (idx == I) {
      constexpr Tup t = META.t[I];
      tuple_impl<t.l, t.l1, t.l2>(fs + b * ROW + t.in1,
                                  fs + b * ROW + t.in2,
                                  out + (size_t)b * TOTCH + t.out_off,
                                  s_re, s_im);
    } else {
      dispatch<I + 1>(idx, b, fs, out, s_re, s_im);
    }
  }
}

__global__ void __launch_bounds__(256)
cg_main(const float* __restrict__ fs, float2* __restrict__ out) {
  // one shared staging buffer sized for the largest tuple (D = 11);
  // declared once at kernel scope so the 111 inlined instantiations share it
  __shared__ float s_re[256 * 11];
  __shared__ float s_im[256 * 11];
  dispatch<0>(blockIdx.x, blockIdx.y, fs, out, s_re, s_im);
}

extern "C" void kernel_launch(void* const* d_in, const int* in_sizes, int n_in,
                              void* d_out, int out_size, void* d_ws, size_t ws_size,
                              hipStream_t stream) {
  const float* fs = (const float*)d_in[0];
  float2* out = (float2*)d_out;
  (void)d_ws; (void)ws_size; (void)in_sizes; (void)n_in; (void)out_size;

  cg_main<<<dim3(NT, NBATCH), dim3(256), 0, stream>>>(fs, out);
}

// Round 2
// 206.730 us; speedup vs baseline: 1.1656x; 1.1366x over previous
//
#include <hip/hip_runtime.h>

#define NT     111
#define LMAX   5
#define TAU    32
#define NBATCH 32
#define ROW    2304   // f32 elements per batch row of fs

struct Tup { int l, l1, l2, out_off, in1, in2; };
struct Meta { Tup t[NT]; int totch; };

constexpr int IN_OFF[LMAX + 1] = {0, 64, 256, 576, 1024, 1600};

constexpr Meta make_meta() {
  Meta m{};
  int n = 0, out = 0;
  for (int l = 0; l <= LMAX; ++l)
    for (int l1 = 0; l1 <= LMAX; ++l1)
      for (int l2 = 0; l2 <= LMAX; ++l2) {
        int df = l1 - l2; if (df < 0) df = -df;
        if (df <= l && l <= l1 + l2) {
          m.t[n].l = l; m.t[n].l1 = l1; m.t[n].l2 = l2;
          m.t[n].out_off = out;
          m.t[n].in1 = IN_OFF[l1]; m.t[n].in2 = IN_OFF[l2];
          out += TAU * TAU * (2 * l + 1);
          ++n;
        }
      }
  m.totch = out;
  return m;
}

constexpr Meta META  = make_meta();
constexpr int  TOTCH = META.totch;   // 789504 complex pairs per batch

// ---------- compile-time CG coefficients ----------
constexpr double cfact(int n) { double r = 1.0; for (int i = 2; i <= n; ++i) r *= i; return r; }

constexpr double csqrt(double x) {
  if (x <= 0.0) return 0.0;
  double g = x;
  for (int i = 0; i < 100; ++i) g = 0.5 * (g + x / g);  // Newton, converges to f64 ulp
  return g;
}

// Condon-Shortley CG coefficient <j1 m1 j2 m2 | j3 m3>, Racah formula, f64 exact factorials.
constexpr double cg_coef_ct(int j1, int m1, int j2, int m2, int j3, int m3) {
  if (m1 + m2 != m3) return 0.0;
  double pref = csqrt((2.0 * j3 + 1.0) * cfact(j3 + j1 - j2) * cfact(j3 - j1 + j2) *
                      cfact(j1 + j2 - j3) / cfact(j1 + j2 + j3 + 1));
  pref *= csqrt(cfact(j3 + m3) * cfact(j3 - m3) * cfact(j1 - m1) * cfact(j1 + m1) *
                cfact(j2 - m2) * cfact(j2 + m2));
  double s = 0.0;
  const int kmax = j1 + j2 - j3;
  for (int k = 0; k <= kmax; ++k) {
    const int a3 = j1 - m1 - k, a4 = j2 + m2 - k, a5 = j3 - j2 + m1 + k, a6 = j3 - j1 - m2 + k;
    if (a3 < 0 || a4 < 0 || a5 < 0 || a6 < 0) continue;
    const double den = cfact(k) * cfact(kmax - k) * cfact(a3) * cfact(a4) * cfact(a5) * cfact(a6);
    s += ((k & 1) ? -1.0 : 1.0) / den;
  }
  return pref * s;
}

// Per-tuple constexpr table (separate variable per tuple keeps each constexpr
// evaluation ~100k steps, under clang's per-initializer limit).
template<int L, int L1, int L2>
struct CGTab {
  struct T { float v[2 * L + 1][2 * L1 + 1][2 * L2 + 1]; };
  static constexpr T gen() {
    T t{};
    for (int m = 0; m < 2 * L + 1; ++m)
      for (int i1 = 0; i1 < 2 * L1 + 1; ++i1)
        for (int i2 = 0; i2 < 2 * L2 + 1; ++i2)
          t.v[m][i1][i2] = (float)cg_coef_ct(L1, i1 - L1, L2, i2 - L2, L, m - L);
    return t;
  }
  static constexpr T tab = gen();
};

// ---------- per-tuple contraction ----------
// Thread t owns (t1,t2) pairs tp = t + 256*j, j=0..3; t2 = t&31 is j-invariant
// (b-fragment registers reused across all 4 j's). The m/i1 loops unroll to
// straight-line FMAs with CG values as immediate constants.
//
// The j-loop is deliberately NOT unrolled (#pragma unroll 1): with 111
// instantiated bodies, 4x j-unrolling made ~1 MB of code -> I$ (32 KB/CU)
// thrash across co-resident blocks. Un-unrolled bodies are <=6 KB each.
//
// Store path: res[D] goes through split re/im LDS planes, then the block
// streams the contiguous 256*D*8B tile out as coalesced float4 (16 B/lane).
template<int L, int L1, int L2>
__device__ __forceinline__ void tuple_impl(const float* __restrict__ fa,
                                           const float* __restrict__ fb,
                                           float2* __restrict__ po,
                                           float* __restrict__ s_re,
                                           float* __restrict__ s_im) {
  constexpr int D = 2 * L + 1, D1 = 2 * L1 + 1, D2 = 2 * L2 + 1;
  const int tid = threadIdx.x;

  const int t2 = tid & 31;
  float br[D2], bi[D2];
  const float2* pb = (const float2*)fb + t2 * D2;
  #pragma unroll
  for (int i = 0; i < D2; ++i) { float2 v = pb[i]; br[i] = v.x; bi[i] = v.y; }

  #pragma unroll 1
  for (int j = 0; j < 4; ++j) {
    const int tp = tid + 256 * j;
    const int t1 = tp >> 5;

    float ar[D1], ai[D1];
    const float2* pa = (const float2*)fa + t1 * D1;
    #pragma unroll
    for (int i = 0; i < D1; ++i) { float2 v = pa[i]; ar[i] = v.x; ai[i] = v.y; }

    float2 res[D];
    #pragma unroll
    for (int m = 0; m < D; ++m) {
      float re = 0.f, im = 0.f;
      #pragma unroll
      for (int i1 = 0; i1 < D1; ++i1) {
        const int i2 = (m - L) - (i1 - L1) + L2;   // unroll-time constant
        if (i2 >= 0 && i2 < D2) {                   // folds after unrolling
          const float c = CGTab<L, L1, L2>::tab.v[m][i1][i2];  // immediate
          if (c != 0.f) {
            re += c * (ar[i1] * br[i2] - ai[i1] * bi[i2]);
            im += c * (ar[i1] * bi[i2] + ai[i1] * br[i2]);
          }
        }
      }
      res[m] = make_float2(re, im);
    }

    // ---- transpose through LDS, store coalesced ----
    __syncthreads();   // previous store-phase readers done before overwrite
    #pragma unroll
    for (int m = 0; m < D; ++m) {
      s_re[tid * D + m] = res[m].x;
      s_im[tid * D + m] = res[m].y;
    }
    __syncthreads();

    // contiguous tile for this j: 256*D float2 = 128*D float4, 16B-aligned
    float4* oj4 = (float4*)(po + (size_t)(256 * j) * D);
    constexpr int NV = 128 * D;                 // float4 count (D odd)
    #pragma unroll
    for (int k = 0; k < (NV + 255) / 256; ++k) {
      const int e = tid + 256 * k;
      if (e < NV) {
        oj4[e] = make_float4(s_re[2 * e], s_im[2 * e],
                             s_re[2 * e + 1], s_im[2 * e + 1]);
      }
    }
  }
}

// ---------- compile-time BINARY dispatch over the 111 tuples ----------
// Depth-7 tree instead of a 111-deep linear if-chain: the old chain forced
// every wave through up to 111 taken branches whose targets spanned the whole
// code image (I$ miss per hop).
template<int LO, int HI>
__device__ __forceinline__ void dispatch(int idx, int b,
                                         const float* __restrict__ fs,
                                         float2* __restrict__ out,
                                         float* __restrict__ s_re,
                                         float* __restrict__ s_im) {
  if constexpr (HI - LO == 1) {
    constexpr Tup t = META.t[LO];
    tuple_impl<t.l, t.l1, t.l2>(fs + b * ROW + t.in1,
                                fs + b * ROW + t.in2,
                                out + (size_t)b * TOTCH + t.out_off,
                                s_re, s_im);
  } else {
    constexpr int MID = LO + (HI - LO) / 2;
    if (idx < MID) dispatch<LO, MID>(idx, b, fs, out, s_re, s_im);
    else           dispatch<MID, HI>(idx, b, fs, out, s_re, s_im);
  }
}

__global__ void __launch_bounds__(256)
cg_main(const float* __restrict__ fs, float2* __restrict__ out) {
  // one shared staging buffer sized for the largest tuple (D = 11);
  // declared once at kernel scope so the 111 inlined instantiations share it
  __shared__ float s_re[256 * 11];
  __shared__ float s_im[256 * 11];
  dispatch<0, NT>(blockIdx.x, blockIdx.y, fs, out, s_re, s_im);
}

extern "C" void kernel_launch(void* const* d_in, const int* in_sizes, int n_in,
                              void* d_out, int out_size, void* d_ws, size_t ws_size,
                              hipStream_t stream) {
  const float* fs = (const float*)d_in[0];
  float2* out = (float2*)d_out;
  (void)d_ws; (void)ws_size; (void)in_sizes; (void)n_in; (void)out_size;

  cg_main<<<dim3(NT, NBATCH), dim3(256), 0, stream>>>(fs, out);
}